// Round 5
// baseline (6312.153 us; speedup 1.0000x reference)
//
#include <hip/hip_runtime.h>
#include <hip/hip_bf16.h>

typedef short s16x8 __attribute__((ext_vector_type(8)));
typedef float f32x4 __attribute__((ext_vector_type(4)));

#define HEADS 24
#define HDIM  128
#define QBLK  54
#define ROWSTRIDE (HEADS * HDIM)   // 3072 floats per canvas position

// rope table offsets (floats) inside d_ws / LDS copy
#define TC 0
#define TS 96
#define YC 192
#define YS 1312
#define XC 2432
#define XS 4224
#define WTOT 6016

__device__ __forceinline__ short f2bf(float f) {
    union { float f; unsigned u; } x; x.f = f;
    unsigned u = (x.u + 0x7fffu + ((x.u >> 16) & 1u)) >> 16;
    return (short)u;
}

// cos/sin lookup for pair index p (0..63) at glued coords (tg, yg, xg)
__device__ __forceinline__ void rope_cs(const float* __restrict__ W, int tg, int yg, int xg,
                                        int p, float& c, float& s) {
    if (p < 8)       { c = W[TC + tg*8  + p];        s = W[TS + tg*8  + p]; }
    else if (p < 36) { int j = p - 8;  c = W[YC + yg*28 + j]; s = W[YS + yg*28 + j]; }
    else             { int j = p - 36; c = W[XC + xg*28 + j]; s = W[XS + xg*28 + j]; }
}

// Build separable RoPE tables on glued canvas. T: 12 pos x 8 pairs (pos=t).
// Y: 40 glued pos x 28 pairs (pos = gy-8). X: 64 glued pos x 28 pairs (pos = gx-8).
// theta=256=2^8: dim16 freq_j = 2^-j ; dim56 freq_j = 2^(-2j/7)
__global__ void rope_tables_k(float* __restrict__ W) {
    int i = blockIdx.x * blockDim.x + threadIdx.x;
    if (i < 96) {
        int t = i >> 3, j = i & 7;
        float ang = (float)t * exp2f(-(float)j);
        float s, c; sincosf(ang, &s, &c);
        W[TC + i] = c; W[TS + i] = s;
    } else if (i < 96 + 1120) {
        int e = i - 96; int gy = e / 28, j = e % 28;
        float ang = (float)(gy - 8) * exp2f(-2.0f * (float)j / 7.0f);
        float s, c; sincosf(ang, &s, &c);
        W[YC + e] = c; W[YS + e] = s;
    } else if (i < 96 + 1120 + 1792) {
        int e = i - 1216; int gx = e / 28, j = e % 28;
        float ang = (float)(gx - 8) * exp2f(-2.0f * (float)j / 7.0f);
        float s, c; sincosf(ang, &s, &c);
        W[XC + e] = c; W[XS + e] = s;
    }
}

// One workgroup = one (q-block, head). 512 threads = 8 waves; wave w owns q rows [32w, 32w+32).
// LDS layout (153.5 KB total, 1 wg/CU):
//   [0, 64K)      Qs (prologue only); after prologue reused as buffer0 {Ks0 [0,16K), Vt0 [16K,34K)}
//   [64K, 98K)    buffer1 {Ks1 [64K,80K), Vt1 [80K,98K)}
//   [98K, 130K)   Ps
//   Wl[6016]      LDS copy of rope tables (kills ~1700 VMEM gathers/wg)
// Swizzles (T2):
//   Ks  [64 rows][128 shorts]: phys_short = (row*128 + col) ^ ((row&7)<<3)   (16B units)
//   Ps  [256 rows][64 shorts]: phys_short = (row*64  + col) ^ ((row&7)<<3)
//   Vt  [128 dims][72 kv]:     phys col-unit u = (kv/8 + dim/16) mod 9, col = u*8 + kv%8
// Pipeline: per chunk c — stageA(c+1) global loads -> QK^T(c) -> softmax -> stageB(c+1)
// LDS writes (other buffer) -> PV(c) -> barrier. One barrier/chunk; loads hide under MFMA.
// NOTE: __launch_bounds__(512,2) is REQUIRED: 512-thread wg needs 2 waves/EU resident;
// VGPR>256 would cap residency at 1 wave/EU and the wg could not launch.
__global__ __launch_bounds__(512, 2) void glued_attn_k(
    const float* __restrict__ Qg, const float* __restrict__ Kg, const float* __restrict__ Vg,
    const float* __restrict__ W, float* __restrict__ Og)
{
    __shared__ __align__(16) char lds[133120];
    __shared__ float Wl[WTOT];
    short* Qs = (short*)lds;                      // 256*128 shorts, prologue only
    short* Ps = (short*)(lds + 100352);           // 256*64 shorts

    const int tid  = threadIdx.x;
    const int wgid = blockIdx.x;
    const int h  = wgid / QBLK;
    const int qb = wgid % QBLK;
    const int bt = qb / 18, by = (qb % 18) / 6, bx = qb % 6;

    // ---- copy rope tables to LDS ----
    for (int i = tid; i < WTOT; i += 512) Wl[i] = W[i];
    __syncthreads();

    // ---- stage Q tile with RoPE, fold log2(e)/sqrt(128) into Q ----
    {
        const int r    = tid >> 1;
        const int half = tid & 1;
        const int it = r >> 6, iy = (r >> 3) & 7, ix = r & 7;
        const int t = bt*4 + it, y = by*8 + iy, x = bx*8 + ix;
        const int l = (t*24 + y)*48 + x;
        const float* src = Qg + (size_t)l * ROWSTRIDE + h * HDIM + half * 64;
        short* dst = &Qs[r * 128 + half * 64];
        const float qscale = 1.442695041f * 0.0883883476f;
#pragma unroll
        for (int j = 0; j < 16; ++j) {
            float4 f = ((const float4*)src)[j];
            int p0 = half * 32 + j * 2;
            float c0, s0, c1, s1;
            rope_cs(Wl, t, y + 8, x + 8, p0,     c0, s0);
            rope_cs(Wl, t, y + 8, x + 8, p0 + 1, c1, s1);
            dst[j*4+0] = f2bf((f.x*c0 - f.y*s0) * qscale);
            dst[j*4+1] = f2bf((f.y*c0 + f.x*s0) * qscale);
            dst[j*4+2] = f2bf((f.z*c1 - f.w*s1) * qscale);
            dst[j*4+3] = f2bf((f.w*c1 + f.z*s1) * qscale);
        }
    }
    __syncthreads();

    const int wv   = tid >> 6;        // wave 0..7
    const int lane = tid & 63;
    const int ln   = lane & 15;
    const int quad = lane >> 4;       // 0..3

    // Q A-frags resident: A[m=ln][k=quad*8+j], k-window ks*32
    s16x8 qf[2][4];
#pragma unroll
    for (int p = 0; p < 2; ++p) {
        const int row = (2*wv + p) * 16 + ln;
#pragma unroll
        for (int ks = 0; ks < 4; ++ks)
            qf[p][ks] = *(const s16x8*)&Qs[row * 128 + ks * 32 + quad * 8];
    }
    __syncthreads();   // Qs region now reusable as buffer0

    f32x4 o[2][8];
#pragma unroll
    for (int p = 0; p < 2; ++p)
#pragma unroll
        for (int dt = 0; dt < 8; ++dt)
            o[p][dt] = (f32x4){0.f, 0.f, 0.f, 0.f};
    float m_r[2][4], l_r[2][4];
#pragma unroll
    for (int p = 0; p < 2; ++p)
#pragma unroll
        for (int r = 0; r < 4; ++r) { m_r[p][r] = -1e30f; l_r[p][r] = 0.f; }

    // ---- staging machinery: thread owns (kv-row kr, dim-segment seg) ----
    const int kr  = tid >> 3;   // 0..63
    const int seg = tid & 7;
    const int d0  = seg * 16;
    float4 kvK[4], kvV[4];      // pending chunk, held across QK^T
    int s_kt, s_ky, s_kx;

    auto stageA = [&](int cc) {   // issue global loads for chunk cc
        const int kb = cc >> 2, ch = cc & 3;
        const int kbt = kb / 9;
        const int kby = by + (kb % 9) / 3;
        const int kbx = bx + (kb % 3);
        s_kt = kbt*4 + ch;
        s_ky = kby*8 + (kr >> 3);
        s_kx = kbx*8 + (kr & 7);
        const int oy = (s_ky + 16) % 24, ox = (s_kx + 40) % 48;   // un-glue (wrap)
        const int lk = (s_kt*24 + oy)*48 + ox;
        const float* srcK = Kg + (size_t)lk * ROWSTRIDE + h * HDIM + d0;
        const float* srcV = Vg + (size_t)lk * ROWSTRIDE + h * HDIM + d0;
#pragma unroll
        for (int j = 0; j < 4; ++j) {
            kvK[j] = ((const float4*)srcK)[j];
            kvV[j] = ((const float4*)srcV)[j];
        }
    };

    auto stageB = [&](short* Kb, short* Vb) {   // rope + convert + LDS write
        s16x8 kv0, kv1;
#pragma unroll
        for (int j = 0; j < 4; ++j) {
            float4 f = kvK[j];
            int p0 = seg*8 + j*2;
            float c0, s0, c1, s1;
            rope_cs(Wl, s_kt, s_ky, s_kx, p0,     c0, s0);
            rope_cs(Wl, s_kt, s_ky, s_kx, p0 + 1, c1, s1);
            short e0 = f2bf(f.x*c0 - f.y*s0);
            short e1 = f2bf(f.y*c0 + f.x*s0);
            short e2 = f2bf(f.z*c1 - f.w*s1);
            short e3 = f2bf(f.w*c1 + f.z*s1);
            if (j < 2) { kv0[j*4+0]=e0; kv0[j*4+1]=e1; kv0[j*4+2]=e2; kv0[j*4+3]=e3; }
            else       { kv1[(j-2)*4+0]=e0; kv1[(j-2)*4+1]=e1; kv1[(j-2)*4+2]=e2; kv1[(j-2)*4+3]=e3; }
        }
        const int kbase = (kr*128 + seg*16) ^ ((kr & 7) << 3);
        *(s16x8*)&Kb[kbase]     = kv0;
        *(s16x8*)&Kb[kbase ^ 8] = kv1;
        int cu = (kr >> 3) + seg; if (cu >= 9) cu -= 9;
        const int vcol = cu * 8 + (kr & 7);
#pragma unroll
        for (int j = 0; j < 4; ++j) {
            float4 f = kvV[j];
            Vb[(d0 + j*4 + 0) * 72 + vcol] = f2bf(f.x);
            Vb[(d0 + j*4 + 1) * 72 + vcol] = f2bf(f.y);
            Vb[(d0 + j*4 + 2) * 72 + vcol] = f2bf(f.z);
            Vb[(d0 + j*4 + 3) * 72 + vcol] = f2bf(f.w);
        }
    };

    // ---- prologue: stage chunk 0 into buffer 0 ----
    stageA(0);
    stageB((short*)lds, (short*)(lds + 16384));
    __syncthreads();

    // ---- main loop: 27 kv-blocks x 4 chunks = 108, double-buffered, 1 barrier/chunk ----
    for (int c = 0; c < 108; ++c) {
        short* Ksc = (short*)(lds + (size_t)(c & 1) * 65536);
        short* Vtc = (short*)(lds + (size_t)(c & 1) * 65536 + 16384);

        if (c < 107) stageA(c + 1);   // global loads in flight during QK^T

        // ---- S = Q K^T (16x16 tiles); share Ks frags across p ----
        f32x4 sa[2][4];
#pragma unroll
        for (int p = 0; p < 2; ++p)
#pragma unroll
            for (int ct = 0; ct < 4; ++ct) sa[p][ct] = (f32x4){0.f, 0.f, 0.f, 0.f};
        __builtin_amdgcn_s_setprio(1);
#pragma unroll
        for (int ct = 0; ct < 4; ++ct) {
            const int krow = ct*16 + ln;
#pragma unroll
            for (int ks = 0; ks < 4; ++ks) {
                s16x8 bf = *(const s16x8*)&Ksc[(krow*128 + ks*32 + quad*8) ^ ((ln & 7) << 3)];
                sa[0][ct] = __builtin_amdgcn_mfma_f32_16x16x32_bf16(qf[0][ks], bf, sa[0][ct], 0, 0, 0);
                sa[1][ct] = __builtin_amdgcn_mfma_f32_16x16x32_bf16(qf[1][ks], bf, sa[1][ct], 0, 0, 0);
            }
        }
        __builtin_amdgcn_s_setprio(0);

        // ---- online softmax per p, P -> LDS (swizzled, wave-private rows) ----
#pragma unroll
        for (int p = 0; p < 2; ++p) {
            float cm[4];
#pragma unroll
            for (int r = 0; r < 4; ++r)
                cm[r] = fmaxf(fmaxf(sa[p][0][r], sa[p][1][r]), fmaxf(sa[p][2][r], sa[p][3][r]));
#pragma unroll
            for (int r = 0; r < 4; ++r) {
                cm[r] = fmaxf(cm[r], __shfl_xor(cm[r], 1));
                cm[r] = fmaxf(cm[r], __shfl_xor(cm[r], 2));
                cm[r] = fmaxf(cm[r], __shfl_xor(cm[r], 4));
                cm[r] = fmaxf(cm[r], __shfl_xor(cm[r], 8));
            }
            float mn[4], al[4], rs[4];
#pragma unroll
            for (int r = 0; r < 4; ++r) {
                mn[r] = fmaxf(m_r[p][r], cm[r]);
                al[r] = exp2f(m_r[p][r] - mn[r]);
                m_r[p][r] = mn[r];
                rs[r] = 0.f;
            }
#pragma unroll
            for (int ct = 0; ct < 4; ++ct)
#pragma unroll
                for (int r = 0; r < 4; ++r) {
                    float pv = exp2f(sa[p][ct][r] - mn[r]);
                    sa[p][ct][r] = pv;
                    rs[r] += pv;
                }
#pragma unroll
            for (int r = 0; r < 4; ++r) {
                rs[r] += __shfl_xor(rs[r], 1);
                rs[r] += __shfl_xor(rs[r], 2);
                rs[r] += __shfl_xor(rs[r], 4);
                rs[r] += __shfl_xor(rs[r], 8);
                l_r[p][r] = l_r[p][r] * al[r] + rs[r];
            }
            const int rowb = (2*wv + p) * 16 + quad * 4;
#pragma unroll
            for (int ct = 0; ct < 4; ++ct)
#pragma unroll
                for (int r = 0; r < 4; ++r) {
                    const int prow = rowb + r;
                    Ps[(prow*64 + ct*16 + ln) ^ ((prow & 7) << 3)] = f2bf(sa[p][ct][r]);
                }
#pragma unroll
            for (int dt = 0; dt < 8; ++dt)
#pragma unroll
                for (int r = 0; r < 4; ++r)
                    o[p][dt][r] *= al[r];
        }

        // ---- write next chunk into the other buffer (hides under softmax/PV) ----
        if (c < 107) {
            short* Ksn = (short*)(lds + (size_t)((c + 1) & 1) * 65536);
            short* Vtn = (short*)(lds + (size_t)((c + 1) & 1) * 65536 + 16384);
            stageB(Ksn, Vtn);
        }

        // ---- O += P V ; share Vt frags across p ----
        {
            const int arow0 = (2*wv + 0) * 16 + ln;
            const int arow1 = (2*wv + 1) * 16 + ln;
            __builtin_amdgcn_s_setprio(1);
#pragma unroll
            for (int ks2 = 0; ks2 < 2; ++ks2) {
                s16x8 a0 = *(const s16x8*)&Ps[(arow0*64 + ks2*32 + quad*8) ^ ((ln & 7) << 3)];
                s16x8 a1 = *(const s16x8*)&Ps[(arow1*64 + ks2*32 + quad*8) ^ ((ln & 7) << 3)];
#pragma unroll
                for (int dt = 0; dt < 8; ++dt) {
                    int u = ks2*4 + quad + dt; if (u >= 9) u -= 9;
                    s16x8 bf = *(const s16x8*)&Vtc[(dt*16 + ln) * 72 + u * 8];
                    o[0][dt] = __builtin_amdgcn_mfma_f32_16x16x32_bf16(a0, bf, o[0][dt], 0, 0, 0);
                    o[1][dt] = __builtin_amdgcn_mfma_f32_16x16x32_bf16(a1, bf, o[1][dt], 0, 0, 0);
                }
            }
            __builtin_amdgcn_s_setprio(0);
        }
        __syncthreads();
    }

    // ---- epilogue: normalize and store fp32 ----
#pragma unroll
    for (int p = 0; p < 2; ++p) {
#pragma unroll
        for (int r = 0; r < 4; ++r) {
            const float inv = 1.0f / l_r[p][r];
            const int rowl = (2*wv + p) * 16 + quad * 4 + r;
            const int it = rowl >> 6, iy = (rowl >> 3) & 7, ix = rowl & 7;
            const int l = ((bt*4 + it)*24 + by*8 + iy)*48 + bx*8 + ix;
            float* dst = Og + (size_t)l * ROWSTRIDE + h * HDIM;
#pragma unroll
            for (int dt = 0; dt < 8; ++dt)
                dst[dt*16 + ln] = o[p][dt][r] * inv;
        }
    }
}

extern "C" void kernel_launch(void* const* d_in, const int* in_sizes, int n_in,
                              void* d_out, int out_size, void* d_ws, size_t ws_size,
                              hipStream_t stream) {
    const float* q = (const float*)d_in[0];
    const float* k = (const float*)d_in[1];
    const float* v = (const float*)d_in[2];
    float* out = (float*)d_out;
    float* W = (float*)d_ws;   // 6016 floats of rope tables

    hipLaunchKernelGGL(rope_tables_k, dim3(12), dim3(256), 0, stream, W);
    hipLaunchKernelGGL(glued_attn_k, dim3(1296), dim3(512), 0, stream, q, k, v, W, out);
}

// Round 6
// 4959.445 us; speedup vs baseline: 1.2728x; 1.2728x over previous
//
#include <hip/hip_runtime.h>
#include <hip/hip_bf16.h>

typedef short s16x8 __attribute__((ext_vector_type(8)));
typedef float f32x4 __attribute__((ext_vector_type(4)));
typedef unsigned int u32x4 __attribute__((ext_vector_type(4)));

#define HEADS 24
#define HDIM  128
#define QBLK  54
#define ROWSTRIDE (HEADS * HDIM)   // 3072 floats per canvas position

// rope table offsets (floats) inside d_ws / LDS copy
#define TC 0
#define TS 96
#define YC 192
#define YS 1312
#define XC 2432
#define XS 4224
#define WTOT 6016

__device__ __forceinline__ short f2bf(float f) {
    union { float f; unsigned u; } x; x.f = f;
    unsigned u = (x.u + 0x7fffu + ((x.u >> 16) & 1u)) >> 16;
    return (short)u;
}

__device__ __forceinline__ unsigned pack2(float a, float b) {
    return (unsigned)(unsigned short)f2bf(a) | ((unsigned)(unsigned short)f2bf(b) << 16);
}

// cos/sin lookup for pair index p (0..63) at glued coords (tg, yg, xg)
__device__ __forceinline__ void rope_cs(const float* __restrict__ W, int tg, int yg, int xg,
                                        int p, float& c, float& s) {
    if (p < 8)       { c = W[TC + tg*8  + p];        s = W[TS + tg*8  + p]; }
    else if (p < 36) { int j = p - 8;  c = W[YC + yg*28 + j]; s = W[YS + yg*28 + j]; }
    else             { int j = p - 36; c = W[XC + xg*28 + j]; s = W[XS + xg*28 + j]; }
}

// Build separable RoPE tables on glued canvas (unchanged).
__global__ void rope_tables_k(float* __restrict__ W) {
    int i = blockIdx.x * blockDim.x + threadIdx.x;
    if (i < 96) {
        int t = i >> 3, j = i & 7;
        float ang = (float)t * exp2f(-(float)j);
        float s, c; sincosf(ang, &s, &c);
        W[TC + i] = c; W[TS + i] = s;
    } else if (i < 96 + 1120) {
        int e = i - 96; int gy = e / 28, j = e % 28;
        float ang = (float)(gy - 8) * exp2f(-2.0f * (float)j / 7.0f);
        float s, c; sincosf(ang, &s, &c);
        W[YC + e] = c; W[YS + e] = s;
    } else if (i < 96 + 1120 + 1792) {
        int e = i - 1216; int gx = e / 28, j = e % 28;
        float ang = (float)(gx - 8) * exp2f(-2.0f * (float)j / 7.0f);
        float s, c; sincosf(ang, &s, &c);
        W[XC + e] = c; W[XS + e] = s;
    }
}

// One workgroup = one (q-block, head). 1024 threads = 16 waves; wave w owns q rows [16w, 16w+16).
// LDS (121.5 KB, 1 wg/CU but 16 waves = 4/SIMD -> needs VGPR<=128, hence launch_bounds(1024,4)):
//   [0, 64K)      Qs (prologue only); after prologue reused as buffer0 {Ks0 [0,16K), Vt0 [16K,34K)}
//   [64K, 98K)    buffer1 {Ks1 [64K,80K), Vt1 [80K,98K)}
//   Wl[6016]      rope tables
// Swizzles: Ks [64][128] shorts: phys = (row*128+col) ^ ((row&7)<<3)  (write & read keys match: row%8)
//           Vt [128 dims][72 kv]: col-unit u = (kv/8 + dim/16) mod 9, col = u*8 + kv%8
// Swapped QK^T: sa = mfma(Kfrag, Qfrag) -> S^T in C-layout: lane(ln,quad) holds
// S[q=ln][kv = ct*16 + quad*4 + r]. Softmax row-reduce = shfl_xor(16)+shfl_xor(32).
// P->PV A-frag: element e of window ks2 on lane(ln,quad) sources lane ln+16*(2*(quad&1)+(e>>2)),
// register pk[2*ks2 + (quad>>1)][(e&3)>>1]  (two-shfl + select, since ct depends on target quad).
__global__ __launch_bounds__(1024, 4) void glued_attn_k(
    const float* __restrict__ Qg, const float* __restrict__ Kg, const float* __restrict__ Vg,
    const float* __restrict__ W, float* __restrict__ Og)
{
    __shared__ __align__(16) char lds[100352];
    __shared__ float Wl[WTOT];
    short* Qs = (short*)lds;    // 256*128 shorts, prologue only

    const int tid  = threadIdx.x;
    const int wgid = blockIdx.x;
    const int h  = wgid / QBLK;
    const int qb = wgid % QBLK;
    const int bt = qb / 18, by = (qb % 18) / 6, bx = qb % 6;

    // ---- copy rope tables to LDS ----
    for (int i = tid; i < WTOT; i += 1024) Wl[i] = W[i];
    __syncthreads();

    // ---- stage Q tile with RoPE, fold log2(e)/sqrt(128) into Q ----
    {
        const int r  = tid >> 2;      // 0..255
        const int qu = tid & 3;       // 32-dim quarter
        const int it = r >> 6, iy = (r >> 3) & 7, ix = r & 7;
        const int t = bt*4 + it, y = by*8 + iy, x = bx*8 + ix;
        const int l = (t*24 + y)*48 + x;
        const float* src = Qg + (size_t)l * ROWSTRIDE + h * HDIM + qu * 32;
        short* dst = &Qs[r * 128 + qu * 32];
        const float qscale = 1.442695041f * 0.0883883476f;
#pragma unroll
        for (int j = 0; j < 8; ++j) {
            float4 f = ((const float4*)src)[j];
            int p0 = qu * 16 + j * 2;
            float c0, s0, c1, s1;
            rope_cs(Wl, t, y + 8, x + 8, p0,     c0, s0);
            rope_cs(Wl, t, y + 8, x + 8, p0 + 1, c1, s1);
            dst[j*4+0] = f2bf((f.x*c0 - f.y*s0) * qscale);
            dst[j*4+1] = f2bf((f.y*c0 + f.x*s0) * qscale);
            dst[j*4+2] = f2bf((f.z*c1 - f.w*s1) * qscale);
            dst[j*4+3] = f2bf((f.w*c1 + f.z*s1) * qscale);
        }
    }
    __syncthreads();

    const int wv   = tid >> 6;        // wave 0..15
    const int lane = tid & 63;
    const int ln   = lane & 15;
    const int quad = lane >> 4;       // 0..3

    // Q A/B-frag resident: frag[m=ln][k=quad*8+j] for row wv*16+ln
    s16x8 qf[4];
    {
        const int row = wv * 16 + ln;
#pragma unroll
        for (int ks = 0; ks < 4; ++ks)
            qf[ks] = *(const s16x8*)&Qs[row * 128 + ks * 32 + quad * 8];
    }
    __syncthreads();   // Qs region now reusable as buffer0

    f32x4 o[8];
#pragma unroll
    for (int dt = 0; dt < 8; ++dt) o[dt] = (f32x4){0.f, 0.f, 0.f, 0.f};
    float m_r = -1e30f, l_r = 0.f;

    // ---- staging: thread owns (kv-row kr, 8-dim segment seg) ----
    const int kr  = tid >> 4;   // 0..63
    const int seg = tid & 15;   // 0..15
    const int d0  = seg * 8;
    float4 kvK[2], kvV[2];
    int s_kt, s_ky, s_kx;

    auto stageA = [&](int cc) {   // issue global loads for chunk cc
        const int kb = cc >> 2, ch = cc & 3;
        const int kbt = kb / 9;
        const int kby = by + (kb % 9) / 3;
        const int kbx = bx + (kb % 3);
        s_kt = kbt*4 + ch;
        s_ky = kby*8 + (kr >> 3);
        s_kx = kbx*8 + (kr & 7);
        const int oy = (s_ky + 16) % 24, ox = (s_kx + 40) % 48;   // un-glue (wrap)
        const int lk = (s_kt*24 + oy)*48 + ox;
        const float* srcK = Kg + (size_t)lk * ROWSTRIDE + h * HDIM + d0;
        const float* srcV = Vg + (size_t)lk * ROWSTRIDE + h * HDIM + d0;
        kvK[0] = ((const float4*)srcK)[0]; kvK[1] = ((const float4*)srcK)[1];
        kvV[0] = ((const float4*)srcV)[0]; kvV[1] = ((const float4*)srcV)[1];
    };

    auto stageB = [&](short* Kb, short* Vb) {   // rope + convert + LDS write
        s16x8 kv0;
#pragma unroll
        for (int j = 0; j < 2; ++j) {
            float4 f = kvK[j];
            int p0 = seg*4 + j*2;
            float c0, s0, c1, s1;
            rope_cs(Wl, s_kt, s_ky, s_kx, p0,     c0, s0);
            rope_cs(Wl, s_kt, s_ky, s_kx, p0 + 1, c1, s1);
            kv0[j*4+0] = f2bf(f.x*c0 - f.y*s0);
            kv0[j*4+1] = f2bf(f.y*c0 + f.x*s0);
            kv0[j*4+2] = f2bf(f.z*c1 - f.w*s1);
            kv0[j*4+3] = f2bf(f.w*c1 + f.z*s1);
        }
        const int kbase = (kr*128 + seg*8) ^ ((kr & 7) << 3);
        *(s16x8*)&Kb[kbase] = kv0;
        int cu = (kr >> 3) + (seg >> 1); if (cu >= 9) cu -= 9;
        const int vcol = cu * 8 + (kr & 7);
#pragma unroll
        for (int j = 0; j < 2; ++j) {
            float4 f = kvV[j];
            Vb[(d0 + j*4 + 0) * 72 + vcol] = f2bf(f.x);
            Vb[(d0 + j*4 + 1) * 72 + vcol] = f2bf(f.y);
            Vb[(d0 + j*4 + 2) * 72 + vcol] = f2bf(f.z);
            Vb[(d0 + j*4 + 3) * 72 + vcol] = f2bf(f.w);
        }
    };

    // ---- prologue: stage chunk 0 into buffer 0 ----
    stageA(0);
    stageB((short*)lds, (short*)(lds + 16384));
    __syncthreads();

    // P redistribution constants
    const int srcA = ln + ((quad & 1) << 5);   // lane ln + 16*(2*(quad&1))
    const int srcB = srcA + 16;
    const bool hi  = (quad >> 1) != 0;         // target quads 2,3 take ct odd

    // ---- main loop: 27 kv-blocks x 4 chunks = 108, double-buffered, 1 barrier/chunk ----
    for (int c = 0; c < 108; ++c) {
        short* Ksc = (short*)(lds + (size_t)(c & 1) * 65536);
        short* Vtc = (short*)(lds + (size_t)(c & 1) * 65536 + 16384);

        if (c < 107) stageA(c + 1);   // global loads in flight during QK^T

        // ---- S^T = K Q^T (swapped operands) ----
        f32x4 sa[4];
#pragma unroll
        for (int ct = 0; ct < 4; ++ct) sa[ct] = (f32x4){0.f, 0.f, 0.f, 0.f};
        __builtin_amdgcn_s_setprio(1);
#pragma unroll
        for (int ct = 0; ct < 4; ++ct) {
            const int krow = ct*16 + ln;
#pragma unroll
            for (int ks = 0; ks < 4; ++ks) {
                s16x8 bf = *(const s16x8*)&Ksc[(krow*128 + ks*32 + quad*8) ^ ((ln & 7) << 3)];
                sa[ct] = __builtin_amdgcn_mfma_f32_16x16x32_bf16(bf, qf[ks], sa[ct], 0, 0, 0);
            }
        }
        __builtin_amdgcn_s_setprio(0);

        // ---- online softmax, fully in-register (lane owns q-row ln of this wave) ----
        float cm = -1e30f;
#pragma unroll
        for (int ct = 0; ct < 4; ++ct)
#pragma unroll
            for (int r = 0; r < 4; ++r) cm = fmaxf(cm, sa[ct][r]);
        cm = fmaxf(cm, __shfl_xor(cm, 16));
        cm = fmaxf(cm, __shfl_xor(cm, 32));
        const float mn = fmaxf(m_r, cm);
        const float al = exp2f(m_r - mn);
        m_r = mn;
        float rs = 0.f;
#pragma unroll
        for (int ct = 0; ct < 4; ++ct)
#pragma unroll
            for (int r = 0; r < 4; ++r) {
                float pv = exp2f(sa[ct][r] - mn);
                sa[ct][r] = pv;
                rs += pv;
            }
        rs += __shfl_xor(rs, 16);
        rs += __shfl_xor(rs, 32);
        l_r = l_r * al + rs;

        unsigned pk[4][2];
#pragma unroll
        for (int ct = 0; ct < 4; ++ct) {
            pk[ct][0] = pack2(sa[ct][0], sa[ct][1]);
            pk[ct][1] = pack2(sa[ct][2], sa[ct][3]);
        }
        // rescale o: need al for output rows quad*4+r (held at lanes 0..15)
        float alr[4];
#pragma unroll
        for (int r = 0; r < 4; ++r) alr[r] = __shfl(al, quad*4 + r);
#pragma unroll
        for (int dt = 0; dt < 8; ++dt)
#pragma unroll
            for (int r = 0; r < 4; ++r) o[dt][r] *= alr[r];

        // ---- write next chunk into the other buffer (hides under PV) ----
        if (c < 107) {
            short* Ksn = (short*)(lds + (size_t)((c + 1) & 1) * 65536);
            short* Vtn = (short*)(lds + (size_t)((c + 1) & 1) * 65536 + 16384);
            stageB(Ksn, Vtn);
        }

        // ---- O += P V : build A-frags from pk via bpermute, consume Vt ----
        __builtin_amdgcn_s_setprio(1);
#pragma unroll
        for (int ks2 = 0; ks2 < 2; ++ks2) {
            unsigned w0e = __shfl(pk[2*ks2][0],   srcA);
            unsigned w0o = __shfl(pk[2*ks2+1][0], srcA);
            unsigned w1e = __shfl(pk[2*ks2][1],   srcA);
            unsigned w1o = __shfl(pk[2*ks2+1][1], srcA);
            unsigned w2e = __shfl(pk[2*ks2][0],   srcB);
            unsigned w2o = __shfl(pk[2*ks2+1][0], srcB);
            unsigned w3e = __shfl(pk[2*ks2][1],   srcB);
            unsigned w3o = __shfl(pk[2*ks2+1][1], srcB);
            union { u32x4 w; s16x8 hh; } cvt;
            cvt.w[0] = hi ? w0o : w0e;
            cvt.w[1] = hi ? w1o : w1e;
            cvt.w[2] = hi ? w2o : w2e;
            cvt.w[3] = hi ? w3o : w3e;
            s16x8 af = cvt.hh;
#pragma unroll
            for (int dt = 0; dt < 8; ++dt) {
                int u = ks2*4 + quad + dt; if (u >= 9) u -= 9;
                s16x8 bf = *(const s16x8*)&Vtc[(dt*16 + ln) * 72 + u * 8];
                o[dt] = __builtin_amdgcn_mfma_f32_16x16x32_bf16(af, bf, o[dt], 0, 0, 0);
            }
        }
        __builtin_amdgcn_s_setprio(0);
        __syncthreads();
    }

    // ---- epilogue: normalize and store fp32 ----
    const float inv_own = 1.0f / l_r;
    float linv[4];
#pragma unroll
    for (int r = 0; r < 4; ++r) linv[r] = __shfl(inv_own, quad*4 + r);
#pragma unroll
    for (int r = 0; r < 4; ++r) {
        const int rowl = wv * 16 + quad * 4 + r;
        const int it = rowl >> 6, iy = (rowl >> 3) & 7, ix = rowl & 7;
        const int l = ((bt*4 + it)*24 + by*8 + iy)*48 + bx*8 + ix;
        float* dst = Og + (size_t)l * ROWSTRIDE + h * HDIM;
#pragma unroll
        for (int dt = 0; dt < 8; ++dt)
            dst[dt*16 + ln] = o[dt][r] * linv[r];
    }
}

extern "C" void kernel_launch(void* const* d_in, const int* in_sizes, int n_in,
                              void* d_out, int out_size, void* d_ws, size_t ws_size,
                              hipStream_t stream) {
    const float* q = (const float*)d_in[0];
    const float* k = (const float*)d_in[1];
    const float* v = (const float*)d_in[2];
    float* out = (float*)d_out;
    float* W = (float*)d_ws;   // 6016 floats of rope tables

    hipLaunchKernelGGL(rope_tables_k, dim3(12), dim3(256), 0, stream, W);
    hipLaunchKernelGGL(glued_attn_k, dim3(1296), dim3(1024), 0, stream, q, k, v, W, out);
}